// Round 1
// baseline (1065.119 us; speedup 1.0000x reference)
//
#include <hip/hip_runtime.h>
#include <hip/hip_bf16.h>
#include <stdint.h>

#define NTOK 49
#define NH 8
#define NWIN 4096

typedef short bf16x8 __attribute__((ext_vector_type(8)));
typedef float f32x4 __attribute__((ext_vector_type(4)));

__device__ __forceinline__ f32x4 mfma16(bf16x8 a, bf16x8 b, f32x4 c) {
    return __builtin_amdgcn_mfma_f32_16x16x32_bf16(a, b, c, 0, 0, 0);
}
__device__ __forceinline__ bf16x8 ld8s(const unsigned short* p) {
    return *(const bf16x8*)p;
}
// packed fp32x2 -> bf16x2 (v_cvt_pk_bf16_f32 on gfx950)
__device__ __forceinline__ unsigned int pk2bf(float a, float b) {
    __hip_bfloat162 h = __float22bfloat162_rn(float2{a, b});
    return *reinterpret_cast<unsigned int*>(&h);
}
// store 4 floats as 4 consecutive bf16 (8B-aligned ds_write_b64)
__device__ __forceinline__ void st4bf(unsigned short* p, float a, float b, float c, float d) {
    uint2 u;
    u.x = pk2bf(a, b);
    u.y = pk2bf(c, d);
    *reinterpret_cast<uint2*>(p) = u;
}
__device__ __forceinline__ bf16x8 pk8(float4 f0, float4 f1) {
    union { bf16x8 v; unsigned int u[4]; } t;
    t.u[0] = pk2bf(f0.x, f0.y);
    t.u[1] = pk2bf(f0.z, f0.w);
    t.u[2] = pk2bf(f1.x, f1.y);
    t.u[3] = pk2bf(f1.z, f1.w);
    return t.v;
}
__device__ __forceinline__ unsigned short f2bf(float f) {
    union { float f; unsigned int u; } v; v.f = f;
    unsigned int r = v.u + 0x7FFFu + ((v.u >> 16) & 1u);
    return (unsigned short)(r >> 16);
}

// ---------------------------------------------------------------------------
// K0: weights -> bf16; expand rel-pos bias to [8][64][64] fp32 with key
// padding mask baked in (-1e30 on key cols >= 49 -> exp() == 0).
// ---------------------------------------------------------------------------
__global__ void prep_kernel(const float* __restrict__ qkv_w,
                            const float* __restrict__ proj_w,
                            const float* __restrict__ bias_table,
                            const int* __restrict__ rel_idx,
                            unsigned short* __restrict__ wqkv,
                            unsigned short* __restrict__ wproj,
                            float* __restrict__ biasx)
{
    int i0 = blockIdx.x * blockDim.x + threadIdx.x;
    int stride = gridDim.x * blockDim.x;
    for (int t = i0; t < 768 * 256; t += stride) wqkv[t] = f2bf(qkv_w[t]);
    for (int t = i0; t < 256 * 256; t += stride) wproj[t] = f2bf(proj_w[t]);
    for (int t = i0; t < NH * 64 * 64; t += stride) {
        int h = t >> 12;
        int m = (t >> 6) & 63;   // query row
        int n = t & 63;          // key col
        float v;
        if (n >= NTOK)      v = -1e30f;
        else if (m >= NTOK) v = 0.0f;
        else                v = bias_table[rel_idx[m * NTOK + n] * NH + h];
        biasx[t] = v;
    }
}

// ---------------------------------------------------------------------------
// K1: fully fused per-window QKV + attention + proj.
// 512 thr = 8 waves; LDS 63488 B -> 2 blocks/CU -> 16 waves/CU (4/SIMD).
//
// Per pass (4 passes x 2 heads):
//   QKV: 24 half-tile jobs (12 channel-tiles x 2 token-halves), 3 per wave.
//        Wave's token half -> xfr[2][8] (64 VGPR), reloaded each pass from
//        global (L2/L3-resident) to stay <=128 VGPR.
//   Attention: wave = (head-local hl = w>>2, query tile qt = w&3).
//        S^T = K·Q^T per 16-query tile; softmax fully in-lane; P never
//        touches LDS: redistributed to the PV B-fragment with 16 ds_bpermute
//        (16-lane-group transpose), so the old "barrier C" disappears.
//   Barriers: 2 per pass (after QKV stores; end of pass) = 9 total per block.
//
// Layout conventions (mfma_f32_16x16x32_bf16):
//   A-frag: a[m = lane&15][k = (lane>>4)*8 + j]
//   B-frag: b[n = lane&15][k = (lane>>4)*8 + j]
//   C/D   : col(n) = lane&15, row(m) = (lane>>4)*4 + reg
// ---------------------------------------------------------------------------
__global__ __launch_bounds__(512, 4) void fused_kernel(
    const float* __restrict__ x,
    const float* __restrict__ qkv_b,
    const unsigned short* __restrict__ wqkv,
    const float* __restrict__ biasx,
    const unsigned short* __restrict__ wproj,
    const float* __restrict__ proj_b,
    float* __restrict__ out)
{
    // 63488 B total -> 2 blocks/CU
    __shared__ unsigned short smem[31744];
    unsigned short* ao = smem;           // [64][264] attnout bf16
    unsigned short* qs = smem + 16896;   // [2][64][40] q*scale
    unsigned short* ks = qs + 5120;      // [2][64][40] k
    unsigned short* vt = ks + 5120;      // [2][32][72] v^T

    const int tid  = threadIdx.x;
    const int wv   = tid >> 6;           // 0..7
    const int lane = tid & 63;
    const int l16  = lane & 15;
    const int lq   = lane >> 4;
    const int w    = blockIdx.x;
    const float scale = 0.17677669529663687f;   // 32^-0.5

    const int wh = wv & 1;    // token half (QKV x-frags + projection)
    const int jt = wv >> 1;   // job group (QKV tile triple / proj tile quad)
    const int hl = wv >> 2;   // attention: head-local within pass
    const int qt = wv & 3;    // attention: query 16-tile

    const float* xw = x + (size_t)w * (NTOK * 256);

#pragma unroll 1
    for (int p = 0; p < 4; ++p) {
        // ---- x B-fragments for this wave's token half (fp32 -> bf16) ----
        bf16x8 xfr[2][8];
#pragma unroll
        for (int nt = 0; nt < 2; ++nt) {
            int tok = wh * 32 + nt * 16 + l16;
#pragma unroll
            for (int c = 0; c < 8; ++c) {
                if (tok < NTOK) {
                    const float* pp = xw + tok * 256 + c * 32 + lq * 8;
                    float4 f0 = *(const float4*)pp;
                    float4 f1 = *(const float4*)(pp + 4);
                    xfr[nt][c] = pk8(f0, f1);
                } else {
                    union { bf16x8 v; unsigned int u[4]; } z;
                    z.u[0] = z.u[1] = z.u[2] = z.u[3] = 0;
                    xfr[nt][c] = z.v;
                }
            }
        }

        // ================= QKV partial GEMM (2 heads) =================
#pragma unroll
        for (int ti = 0; ti < 3; ++ti) {
            int tld  = jt * 3 + ti;            // 0..11
            int grp  = tld >> 2;               // 0=q 1=k 2=v
            int sub  = tld & 3;
            int tile = grp * 16 + p * 4 + sub; // of 48
            const unsigned short* bptr = wqkv + (size_t)(tile * 16 + l16) * 256 + lq * 8;
            bf16x8 bfr[8];
#pragma unroll
            for (int c = 0; c < 8; ++c) bfr[c] = ld8s(bptr + c * 32);

            f32x4 acc[2];
            { f32x4 z = {0.f,0.f,0.f,0.f}; acc[0] = z; acc[1] = z; }

            if (grp < 2) {
                // swapped: D[ch][tok] -> packed writes along d
#pragma unroll
                for (int c = 0; c < 8; ++c)
#pragma unroll
                    for (int nt = 0; nt < 2; ++nt)
                        acc[nt] = mfma16(bfr[c], xfr[nt][c], acc[nt]);
                int chb = tile * 16 + lq * 4;          // global channel base
                float4 bv = *(const float4*)(qkv_b + chb);
                int c0 = chb & 255;
                int hh = (c0 >> 5) & 1, d0 = c0 & 31;
                unsigned short* dst = (grp == 0 ? qs : ks) + (hh * 64) * 40 + d0;
                float sc = (grp == 0) ? scale : 1.0f;
#pragma unroll
                for (int nt = 0; nt < 2; ++nt) {
                    int tok = wh * 32 + nt * 16 + l16;
                    st4bf(dst + tok * 40,
                          (acc[nt][0] + bv.x) * sc, (acc[nt][1] + bv.y) * sc,
                          (acc[nt][2] + bv.z) * sc, (acc[nt][3] + bv.w) * sc);
                }
            } else {
                // original: D[tok][ch] -> packed writes along tok into v^T
#pragma unroll
                for (int c = 0; c < 8; ++c)
#pragma unroll
                    for (int nt = 0; nt < 2; ++nt)
                        acc[nt] = mfma16(xfr[nt][c], bfr[c], acc[nt]);
                int ch = tile * 16 + l16;
                float bv = qkv_b[ch];
                int c0 = ch & 255;
                int hh = (c0 >> 5) & 1, d = c0 & 31;
                unsigned short* dst = vt + (hh * 32 + d) * 72;
#pragma unroll
                for (int nt = 0; nt < 2; ++nt) {
                    int tok0 = wh * 32 + nt * 16 + lq * 4;
                    st4bf(dst + tok0, acc[nt][0] + bv, acc[nt][1] + bv,
                                      acc[nt][2] + bv, acc[nt][3] + bv);
                }
            }
        }
        __syncthreads();   // (B) q/k/v visible

        // ================= attention: Sᵀ = K·Qᵀ =================
        const int h = 2 * p + hl;
        bf16x8 kf[4];
#pragma unroll
        for (int mt = 0; mt < 4; ++mt)
            kf[mt] = ld8s(&ks[(hl * 64 + mt * 16 + l16) * 40 + lq * 8]);
        bf16x8 qf = ld8s(&qs[(hl * 64 + qt * 16 + l16) * 40 + lq * 8]);

        f32x4 se[4];
#pragma unroll
        for (int mt = 0; mt < 4; ++mt) { f32x4 z = {0.f,0.f,0.f,0.f}; se[mt] = z; }
#pragma unroll
        for (int mt = 0; mt < 4; ++mt)
            se[mt] = mfma16(kf[mt], qf, se[mt]);
        // lane holds: query = qt*16 + l16, key = mt*16 + lq*4 + r

        // bias + exp + in-lane sum (no max-subtract: |s| bounded ~15)
        const int q = qt * 16 + l16;
        const float* bh = biasx + (h << 12);
        float lsum = 0.0f;
#pragma unroll
        for (int mt = 0; mt < 4; ++mt) {
            float4 bb = *(const float4*)(bh + q * 64 + mt * 16 + lq * 4);
            float e0 = __expf(se[mt][0] + bb.x);
            float e1 = __expf(se[mt][1] + bb.y);
            float e2 = __expf(se[mt][2] + bb.z);
            float e3 = __expf(se[mt][3] + bb.w);
            se[mt][0] = e0; se[mt][1] = e1;
            se[mt][2] = e2; se[mt][3] = e3;
            lsum += (e0 + e1) + (e2 + e3);
        }
        lsum += __shfl_xor(lsum, 16);
        lsum += __shfl_xor(lsum, 32);
        float rv = 1.0f / lsum;

        // pack normalized P: P0[mt] = keys (lq*4+0,1), P1[mt] = keys (lq*4+2,3)
        unsigned int P0[4], P1[4];
#pragma unroll
        for (int mt = 0; mt < 4; ++mt) {
            P0[mt] = pk2bf(se[mt][0] * rv, se[mt][1] * rv);
            P1[mt] = pk2bf(se[mt][2] * rv, se[mt][3] * rv);
        }
        // redistribute to PV B-frag in-register (16-lane-group transpose):
        // pf[kc] dword dj holds keys kc*32 + lq*8 + 2*dj(+1); the owner of
        // key K is lane (l16, (K>>2)&3), regs P{0,1}[K>>4].
        int srcA = l16 + ((2 * lq) & 3) * 16;
        int srcB = srcA + 16;            // ((2*lq+1)&3)*16 == srcA+16 always
        int hi = lq >> 1;                // selects mt' = 2*kc + (lq>>1)
        bf16x8 pf[2];
#pragma unroll
        for (int kc = 0; kc < 2; ++kc) {
            unsigned int a0 = (unsigned int)__shfl((int)P0[2 * kc],     srcA);
            unsigned int a1 = (unsigned int)__shfl((int)P0[2 * kc + 1], srcA);
            unsigned int b0 = (unsigned int)__shfl((int)P1[2 * kc],     srcA);
            unsigned int b1 = (unsigned int)__shfl((int)P1[2 * kc + 1], srcA);
            unsigned int c0 = (unsigned int)__shfl((int)P0[2 * kc],     srcB);
            unsigned int c1 = (unsigned int)__shfl((int)P0[2 * kc + 1], srcB);
            unsigned int d0 = (unsigned int)__shfl((int)P1[2 * kc],     srcB);
            unsigned int d1 = (unsigned int)__shfl((int)P1[2 * kc + 1], srcB);
            union { bf16x8 v; unsigned int u[4]; } t;
            t.u[0] = hi ? a1 : a0;
            t.u[1] = hi ? b1 : b0;
            t.u[2] = hi ? c1 : c0;
            t.u[3] = hi ? d1 : d0;
            pf[kc] = t.v;
        }

        // ================= Oᵀ = Vᵀ·P =================
        bf16x8 vf[2][2];
#pragma unroll
        for (int kc = 0; kc < 2; ++kc)
#pragma unroll
            for (int mt = 0; mt < 2; ++mt)
                vf[mt][kc] = ld8s(&vt[(hl * 32 + mt * 16 + l16) * 72 + kc * 32 + lq * 8]);

        f32x4 ot[2];
        { f32x4 z = {0.f,0.f,0.f,0.f}; ot[0] = z; ot[1] = z; }
#pragma unroll
        for (int kc = 0; kc < 2; ++kc)
#pragma unroll
            for (int mt = 0; mt < 2; ++mt)
                ot[mt] = mfma16(vf[mt][kc], pf[kc], ot[mt]);
        // lane holds: d = mt*16 + lq*4 + r, query = qt*16 + l16

#pragma unroll
        for (int mt = 0; mt < 2; ++mt)
            st4bf(&ao[q * 264 + h * 32 + mt * 16 + lq * 4],
                  ot[mt][0], ot[mt][1], ot[mt][2], ot[mt][3]);
        __syncthreads();   // (E) q/k/v consumed; ao slice written
    }

    // ================= projection from LDS attnout =================
    bf16x8 af2[2][8];
#pragma unroll
    for (int nt = 0; nt < 2; ++nt)
#pragma unroll
        for (int c = 0; c < 8; ++c)
            af2[nt][c] = ld8s(&ao[(wh * 32 + nt * 16 + l16) * 264 + c * 32 + lq * 8]);

#pragma unroll
    for (int t4 = 0; t4 < 4; ++t4) {
        int tile = jt * 4 + t4;            // 16 channel-tiles x 2 halves
        const unsigned short* wp = wproj + (size_t)(tile * 16 + l16) * 256 + lq * 8;
        bf16x8 wfr[8];
#pragma unroll
        for (int c = 0; c < 8; ++c) wfr[c] = ld8s(wp + c * 32);

        f32x4 acc[2];
        { f32x4 z = {0.f,0.f,0.f,0.f}; acc[0] = z; acc[1] = z; }
#pragma unroll
        for (int c = 0; c < 8; ++c)
#pragma unroll
            for (int nt = 0; nt < 2; ++nt)
                acc[nt] = mfma16(wfr[c], af2[nt][c], acc[nt]);

        int chb = tile * 16 + lq * 4;
        float4 pb = *(const float4*)(proj_b + chb);
#pragma unroll
        for (int nt = 0; nt < 2; ++nt) {
            int tok = wh * 32 + nt * 16 + l16;
            if (tok < NTOK) {
                float4 o;
                o.x = acc[nt][0] + pb.x;
                o.y = acc[nt][1] + pb.y;
                o.z = acc[nt][2] + pb.z;
                o.w = acc[nt][3] + pb.w;
                *(float4*)(out + ((size_t)w * NTOK + tok) * 256 + chb) = o;
            }
        }
    }
}

// ---------------------------------------------------------------------------
extern "C" void kernel_launch(void* const* d_in, const int* in_sizes, int n_in,
                              void* d_out, int out_size, void* d_ws, size_t ws_size,
                              hipStream_t stream) {
    const float* x          = (const float*)d_in[0];
    const float* qkv_w      = (const float*)d_in[1];
    const float* qkv_b      = (const float*)d_in[2];
    const float* proj_w     = (const float*)d_in[3];
    const float* proj_b     = (const float*)d_in[4];
    const float* bias_table = (const float*)d_in[5];
    const int*   rel_idx    = (const int*)d_in[6];
    float* out = (float*)d_out;

    char* ws = (char*)d_ws;
    unsigned short* wqkv  = (unsigned short*)ws;                 // 393216 B
    unsigned short* wproj = (unsigned short*)(ws + 393216);      // 131072 B
    float*          biasx = (float*)(ws + 524288);               // 131072 B

    prep_kernel<<<256, 256, 0, stream>>>(qkv_w, proj_w, bias_table, rel_idx,
                                         wqkv, wproj, biasx);
    fused_kernel<<<NWIN, 512, 0, stream>>>(x, qkv_b, wqkv, biasx, wproj,
                                           proj_b, out);
}

// Round 2
// 981.655 us; speedup vs baseline: 1.0850x; 1.0850x over previous
//
#include <hip/hip_runtime.h>
#include <hip/hip_bf16.h>
#include <stdint.h>

#define NTOK 49
#define NH 8
#define NWIN 4096

typedef short bf16x8 __attribute__((ext_vector_type(8)));
typedef float f32x4 __attribute__((ext_vector_type(4)));

__device__ __forceinline__ f32x4 mfma16(bf16x8 a, bf16x8 b, f32x4 c) {
    return __builtin_amdgcn_mfma_f32_16x16x32_bf16(a, b, c, 0, 0, 0);
}
__device__ __forceinline__ bf16x8 ld8s(const unsigned short* p) {
    return *(const bf16x8*)p;
}
// packed fp32x2 -> bf16x2 (v_cvt_pk_bf16_f32 on gfx950)
__device__ __forceinline__ unsigned int pk2bf(float a, float b) {
    __hip_bfloat162 h = __float22bfloat162_rn(float2{a, b});
    return *reinterpret_cast<unsigned int*>(&h);
}
// store 4 floats as 4 consecutive bf16 (8B-aligned ds_write_b64)
__device__ __forceinline__ void st4bf(unsigned short* p, float a, float b, float c, float d) {
    uint2 u;
    u.x = pk2bf(a, b);
    u.y = pk2bf(c, d);
    *reinterpret_cast<uint2*>(p) = u;
}
__device__ __forceinline__ bf16x8 pk8(float4 f0, float4 f1) {
    union { bf16x8 v; unsigned int u[4]; } t;
    t.u[0] = pk2bf(f0.x, f0.y);
    t.u[1] = pk2bf(f0.z, f0.w);
    t.u[2] = pk2bf(f1.x, f1.y);
    t.u[3] = pk2bf(f1.z, f1.w);
    return t.v;
}
__device__ __forceinline__ unsigned short f2bf(float f) {
    union { float f; unsigned int u; } v; v.f = f;
    unsigned int r = v.u + 0x7FFFu + ((v.u >> 16) & 1u);
    return (unsigned short)(r >> 16);
}

// ---------------------------------------------------------------------------
// K0: weights -> bf16; expand rel-pos bias to [8][64][64] fp32 with key
// padding mask baked in (-1e30 on key cols >= 49 -> exp() == 0).
// ---------------------------------------------------------------------------
__global__ void prep_kernel(const float* __restrict__ qkv_w,
                            const float* __restrict__ proj_w,
                            const float* __restrict__ bias_table,
                            const int* __restrict__ rel_idx,
                            unsigned short* __restrict__ wqkv,
                            unsigned short* __restrict__ wproj,
                            float* __restrict__ biasx)
{
    int i0 = blockIdx.x * blockDim.x + threadIdx.x;
    int stride = gridDim.x * blockDim.x;
    for (int t = i0; t < 768 * 256; t += stride) wqkv[t] = f2bf(qkv_w[t]);
    for (int t = i0; t < 256 * 256; t += stride) wproj[t] = f2bf(proj_w[t]);
    for (int t = i0; t < NH * 64 * 64; t += stride) {
        int h = t >> 12;
        int m = (t >> 6) & 63;   // query row
        int n = t & 63;          // key col
        float v;
        if (n >= NTOK)      v = -1e30f;
        else if (m >= NTOK) v = 0.0f;
        else                v = bias_table[rel_idx[m * NTOK + n] * NH + h];
        biasx[t] = v;
    }
}

// ---------------------------------------------------------------------------
// K1: fully fused per-window QKV + attention + proj.
// 512 thr = 8 waves; LDS 63488 B -> 2 blocks/CU -> 16 waves/CU (4/SIMD).
//
// __launch_bounds__(512, 2): the 2nd arg is CUDA-style min BLOCKS/CU on this
// toolchain (R1 evidence: (512,4) produced a 64-VGPR cap = 4 blocks x 8
// waves = 8 waves/SIMD, with 220 MB of scratch spill). 2 blocks -> 16
// waves/CU -> cap 128 VGPR, matching the LDS limit exactly.
//
// Per pass (4 passes x 2 heads):
//   QKV: 24 half-tile jobs (12 channel-tiles x 2 token-halves), 3 per wave.
//        Wave's token half lives in xfr[2][8] (64 VGPR), loaded ONCE.
//   Attention: wave = (head-local hl = w>>2, query tile qt = w&3).
//        S^T = K·Q^T per 16-query tile; softmax fully in-lane; P never
//        touches LDS: redistributed to the PV B-fragment with 16 shuffles
//        (16-lane-group transpose) -> no P barrier.
//   Barriers: 2 per pass = 9 total per block (was 13 in the 256-thr version).
//
// Layout conventions (mfma_f32_16x16x32_bf16):
//   A-frag: a[m = lane&15][k = (lane>>4)*8 + j]
//   B-frag: b[n = lane&15][k = (lane>>4)*8 + j]
//   C/D   : col(n) = lane&15, row(m) = (lane>>4)*4 + reg
// ---------------------------------------------------------------------------
__global__ __launch_bounds__(512, 2) void fused_kernel(
    const float* __restrict__ x,
    const float* __restrict__ qkv_b,
    const unsigned short* __restrict__ wqkv,
    const float* __restrict__ biasx,
    const unsigned short* __restrict__ wproj,
    const float* __restrict__ proj_b,
    float* __restrict__ out)
{
    // 63488 B total -> 2 blocks/CU
    __shared__ unsigned short smem[31744];
    unsigned short* ao = smem;           // [64][264] attnout bf16
    unsigned short* qs = smem + 16896;   // [2][64][40] q*scale
    unsigned short* ks = qs + 5120;      // [2][64][40] k
    unsigned short* vt = ks + 5120;      // [2][32][72] v^T

    const int tid  = threadIdx.x;
    const int wv   = tid >> 6;           // 0..7
    const int lane = tid & 63;
    const int l16  = lane & 15;
    const int lq   = lane >> 4;
    const int w    = blockIdx.x;
    const float scale = 0.17677669529663687f;   // 32^-0.5

    const int wh = wv & 1;    // token half (QKV x-frags + projection)
    const int jt = wv >> 1;   // job group (QKV tile triple / proj tile quad)
    const int hl = wv >> 2;   // attention: head-local within pass
    const int qt = wv & 3;    // attention: query 16-tile

    const float* xw = x + (size_t)w * (NTOK * 256);

    // ---- x B-fragments for this wave's token half (fp32 -> bf16), ONCE ----
    bf16x8 xfr[2][8];
#pragma unroll
    for (int nt = 0; nt < 2; ++nt) {
        int tok = wh * 32 + nt * 16 + l16;
#pragma unroll
        for (int c = 0; c < 8; ++c) {
            if (tok < NTOK) {
                const float* pp = xw + tok * 256 + c * 32 + lq * 8;
                float4 f0 = *(const float4*)pp;
                float4 f1 = *(const float4*)(pp + 4);
                xfr[nt][c] = pk8(f0, f1);
            } else {
                union { bf16x8 v; unsigned int u[4]; } z;
                z.u[0] = z.u[1] = z.u[2] = z.u[3] = 0;
                xfr[nt][c] = z.v;
            }
        }
    }

#pragma unroll 1
    for (int p = 0; p < 4; ++p) {
        // ================= QKV partial GEMM (2 heads) =================
#pragma unroll
        for (int ti = 0; ti < 3; ++ti) {
            int tld  = jt * 3 + ti;            // 0..11
            int grp  = tld >> 2;               // 0=q 1=k 2=v
            int sub  = tld & 3;
            int tile = grp * 16 + p * 4 + sub; // of 48
            const unsigned short* bptr = wqkv + (size_t)(tile * 16 + l16) * 256 + lq * 8;
            bf16x8 bfr[8];
#pragma unroll
            for (int c = 0; c < 8; ++c) bfr[c] = ld8s(bptr + c * 32);

            f32x4 acc[2];
            { f32x4 z = {0.f,0.f,0.f,0.f}; acc[0] = z; acc[1] = z; }

            if (grp < 2) {
                // swapped: D[ch][tok] -> packed writes along d
#pragma unroll
                for (int c = 0; c < 8; ++c)
#pragma unroll
                    for (int nt = 0; nt < 2; ++nt)
                        acc[nt] = mfma16(bfr[c], xfr[nt][c], acc[nt]);
                int chb = tile * 16 + lq * 4;          // global channel base
                float4 bv = *(const float4*)(qkv_b + chb);
                int c0 = chb & 255;
                int hh = (c0 >> 5) & 1, d0 = c0 & 31;
                unsigned short* dst = (grp == 0 ? qs : ks) + (hh * 64) * 40 + d0;
                float sc = (grp == 0) ? scale : 1.0f;
#pragma unroll
                for (int nt = 0; nt < 2; ++nt) {
                    int tok = wh * 32 + nt * 16 + l16;
                    st4bf(dst + tok * 40,
                          (acc[nt][0] + bv.x) * sc, (acc[nt][1] + bv.y) * sc,
                          (acc[nt][2] + bv.z) * sc, (acc[nt][3] + bv.w) * sc);
                }
            } else {
                // original: D[tok][ch] -> packed writes along tok into v^T
#pragma unroll
                for (int c = 0; c < 8; ++c)
#pragma unroll
                    for (int nt = 0; nt < 2; ++nt)
                        acc[nt] = mfma16(xfr[nt][c], bfr[c], acc[nt]);
                int ch = tile * 16 + l16;
                float bv = qkv_b[ch];
                int c0 = ch & 255;
                int hh = (c0 >> 5) & 1, d = c0 & 31;
                unsigned short* dst = vt + (hh * 32 + d) * 72;
#pragma unroll
                for (int nt = 0; nt < 2; ++nt) {
                    int tok0 = wh * 32 + nt * 16 + lq * 4;
                    st4bf(dst + tok0, acc[nt][0] + bv, acc[nt][1] + bv,
                                      acc[nt][2] + bv, acc[nt][3] + bv);
                }
            }
        }
        __syncthreads();   // (B) q/k/v visible

        // ================= attention: Sᵀ = K·Qᵀ =================
        const int h = 2 * p + hl;
        bf16x8 kf[4];
#pragma unroll
        for (int mt = 0; mt < 4; ++mt)
            kf[mt] = ld8s(&ks[(hl * 64 + mt * 16 + l16) * 40 + lq * 8]);
        bf16x8 qf = ld8s(&qs[(hl * 64 + qt * 16 + l16) * 40 + lq * 8]);

        f32x4 se[4];
#pragma unroll
        for (int mt = 0; mt < 4; ++mt) { f32x4 z = {0.f,0.f,0.f,0.f}; se[mt] = z; }
#pragma unroll
        for (int mt = 0; mt < 4; ++mt)
            se[mt] = mfma16(kf[mt], qf, se[mt]);
        // lane holds: query = qt*16 + l16, key = mt*16 + lq*4 + r

        // bias + exp + in-lane sum (no max-subtract: |s| bounded ~15)
        const int q = qt * 16 + l16;
        const float* bh = biasx + (h << 12);
        float lsum = 0.0f;
#pragma unroll
        for (int mt = 0; mt < 4; ++mt) {
            float4 bb = *(const float4*)(bh + q * 64 + mt * 16 + lq * 4);
            float e0 = __expf(se[mt][0] + bb.x);
            float e1 = __expf(se[mt][1] + bb.y);
            float e2 = __expf(se[mt][2] + bb.z);
            float e3 = __expf(se[mt][3] + bb.w);
            se[mt][0] = e0; se[mt][1] = e1;
            se[mt][2] = e2; se[mt][3] = e3;
            lsum += (e0 + e1) + (e2 + e3);
        }
        lsum += __shfl_xor(lsum, 16);
        lsum += __shfl_xor(lsum, 32);
        float rv = 1.0f / lsum;

        // pack normalized P: P0[mt] = keys (lq*4+0,1), P1[mt] = keys (lq*4+2,3)
        unsigned int P0[4], P1[4];
#pragma unroll
        for (int mt = 0; mt < 4; ++mt) {
            P0[mt] = pk2bf(se[mt][0] * rv, se[mt][1] * rv);
            P1[mt] = pk2bf(se[mt][2] * rv, se[mt][3] * rv);
        }
        // redistribute to PV B-frag in-register (16-lane-group transpose):
        // pf[kc] dword dj holds keys kc*32 + lq*8 + 2*dj(+1); the owner of
        // key K is lane (l16, (K>>2)&3), regs P{0,1}[K>>4].
        int srcA = l16 + ((2 * lq) & 3) * 16;
        int srcB = srcA + 16;            // ((2*lq+1)&3)*16 == srcA+16 always
        int hi = lq >> 1;                // selects mt' = 2*kc + (lq>>1)
        bf16x8 pf[2];
#pragma unroll
        for (int kc = 0; kc < 2; ++kc) {
            unsigned int a0 = (unsigned int)__shfl((int)P0[2 * kc],     srcA);
            unsigned int a1 = (unsigned int)__shfl((int)P0[2 * kc + 1], srcA);
            unsigned int b0 = (unsigned int)__shfl((int)P1[2 * kc],     srcA);
            unsigned int b1 = (unsigned int)__shfl((int)P1[2 * kc + 1], srcA);
            unsigned int c0 = (unsigned int)__shfl((int)P0[2 * kc],     srcB);
            unsigned int c1 = (unsigned int)__shfl((int)P0[2 * kc + 1], srcB);
            unsigned int d0 = (unsigned int)__shfl((int)P1[2 * kc],     srcB);
            unsigned int d1 = (unsigned int)__shfl((int)P1[2 * kc + 1], srcB);
            union { bf16x8 v; unsigned int u[4]; } t;
            t.u[0] = hi ? a1 : a0;
            t.u[1] = hi ? b1 : b0;
            t.u[2] = hi ? c1 : c0;
            t.u[3] = hi ? d1 : d0;
            pf[kc] = t.v;
        }

        // ================= Oᵀ = Vᵀ·P =================
        bf16x8 vf[2][2];
#pragma unroll
        for (int kc = 0; kc < 2; ++kc)
#pragma unroll
            for (int mt = 0; mt < 2; ++mt)
                vf[mt][kc] = ld8s(&vt[(hl * 32 + mt * 16 + l16) * 72 + kc * 32 + lq * 8]);

        f32x4 ot[2];
        { f32x4 z = {0.f,0.f,0.f,0.f}; ot[0] = z; ot[1] = z; }
#pragma unroll
        for (int kc = 0; kc < 2; ++kc)
#pragma unroll
            for (int mt = 0; mt < 2; ++mt)
                ot[mt] = mfma16(vf[mt][kc], pf[kc], ot[mt]);
        // lane holds: d = mt*16 + lq*4 + r, query = qt*16 + l16

#pragma unroll
        for (int mt = 0; mt < 2; ++mt)
            st4bf(&ao[q * 264 + h * 32 + mt * 16 + lq * 4],
                  ot[mt][0], ot[mt][1], ot[mt][2], ot[mt][3]);
        __syncthreads();   // (E) q/k/v consumed; ao slice written
    }

    // ================= projection from LDS attnout =================
    bf16x8 af2[2][8];
#pragma unroll
    for (int nt = 0; nt < 2; ++nt)
#pragma unroll
        for (int c = 0; c < 8; ++c)
            af2[nt][c] = ld8s(&ao[(wh * 32 + nt * 16 + l16) * 264 + c * 32 + lq * 8]);

#pragma unroll
    for (int t4 = 0; t4 < 4; ++t4) {
        int tile = jt * 4 + t4;            // 16 channel-tiles x 2 halves
        const unsigned short* wp = wproj + (size_t)(tile * 16 + l16) * 256 + lq * 8;
        bf16x8 wfr[8];
#pragma unroll
        for (int c = 0; c < 8; ++c) wfr[c] = ld8s(wp + c * 32);

        f32x4 acc[2];
        { f32x4 z = {0.f,0.f,0.f,0.f}; acc[0] = z; acc[1] = z; }
#pragma unroll
        for (int c = 0; c < 8; ++c)
#pragma unroll
            for (int nt = 0; nt < 2; ++nt)
                acc[nt] = mfma16(wfr[c], af2[nt][c], acc[nt]);

        int chb = tile * 16 + lq * 4;
        float4 pb = *(const float4*)(proj_b + chb);
#pragma unroll
        for (int nt = 0; nt < 2; ++nt) {
            int tok = wh * 32 + nt * 16 + l16;
            if (tok < NTOK) {
                float4 o;
                o.x = acc[nt][0] + pb.x;
                o.y = acc[nt][1] + pb.y;
                o.z = acc[nt][2] + pb.z;
                o.w = acc[nt][3] + pb.w;
                *(float4*)(out + ((size_t)w * NTOK + tok) * 256 + chb) = o;
            }
        }
    }
}

// ---------------------------------------------------------------------------
extern "C" void kernel_launch(void* const* d_in, const int* in_sizes, int n_in,
                              void* d_out, int out_size, void* d_ws, size_t ws_size,
                              hipStream_t stream) {
    const float* x          = (const float*)d_in[0];
    const float* qkv_b      = (const float*)d_in[2];
    const float* qkv_w      = (const float*)d_in[1];
    const float* proj_w     = (const float*)d_in[3];
    const float* proj_b     = (const float*)d_in[4];
    const float* bias_table = (const float*)d_in[5];
    const int*   rel_idx    = (const int*)d_in[6];
    float* out = (float*)d_out;

    char* ws = (char*)d_ws;
    unsigned short* wqkv  = (unsigned short*)ws;                 // 393216 B
    unsigned short* wproj = (unsigned short*)(ws + 393216);      // 131072 B
    float*          biasx = (float*)(ws + 524288);               // 131072 B

    prep_kernel<<<256, 256, 0, stream>>>(qkv_w, proj_w, bias_table, rel_idx,
                                         wqkv, wproj, biasx);
    fused_kernel<<<NWIN, 512, 0, stream>>>(x, qkv_b, wqkv, biasx, wproj,
                                           proj_b, out);
}

// Round 3
// 839.268 us; speedup vs baseline: 1.2691x; 1.1697x over previous
//
#include <hip/hip_runtime.h>
#include <hip/hip_bf16.h>
#include <stdint.h>

#define NTOK 49
#define NH 8
#define NWIN 4096

typedef short bf16x8 __attribute__((ext_vector_type(8)));
typedef float f32x4 __attribute__((ext_vector_type(4)));

__device__ __forceinline__ f32x4 mfma16(bf16x8 a, bf16x8 b, f32x4 c) {
    return __builtin_amdgcn_mfma_f32_16x16x32_bf16(a, b, c, 0, 0, 0);
}
__device__ __forceinline__ bf16x8 ld8s(const unsigned short* p) {
    return *(const bf16x8*)p;
}
// packed fp32x2 -> bf16x2 (v_cvt_pk_bf16_f32 on gfx950)
__device__ __forceinline__ unsigned int pk2bf(float a, float b) {
    __hip_bfloat162 h = __float22bfloat162_rn(float2{a, b});
    return *reinterpret_cast<unsigned int*>(&h);
}
// store 4 floats as 4 consecutive bf16 (8B-aligned ds_write_b64)
__device__ __forceinline__ void st4bf(unsigned short* p, float a, float b, float c, float d) {
    uint2 u;
    u.x = pk2bf(a, b);
    u.y = pk2bf(c, d);
    *reinterpret_cast<uint2*>(p) = u;
}
__device__ __forceinline__ bf16x8 pk8(float4 f0, float4 f1) {
    union { bf16x8 v; unsigned int u[4]; } t;
    t.u[0] = pk2bf(f0.x, f0.y);
    t.u[1] = pk2bf(f0.z, f0.w);
    t.u[2] = pk2bf(f1.x, f1.y);
    t.u[3] = pk2bf(f1.z, f1.w);
    return t.v;
}
__device__ __forceinline__ unsigned short f2bf(float f) {
    union { float f; unsigned int u; } v; v.f = f;
    unsigned int r = v.u + 0x7FFFu + ((v.u >> 16) & 1u);
    return (unsigned short)(r >> 16);
}

// ---------------------------------------------------------------------------
// K0: weights -> bf16; expand rel-pos bias to [8][64][64] fp32 with key
// padding mask baked in (-1e30 on key cols >= 49 -> exp() == 0).
// ---------------------------------------------------------------------------
__global__ void prep_kernel(const float* __restrict__ qkv_w,
                            const float* __restrict__ proj_w,
                            const float* __restrict__ bias_table,
                            const int* __restrict__ rel_idx,
                            unsigned short* __restrict__ wqkv,
                            unsigned short* __restrict__ wproj,
                            float* __restrict__ biasx)
{
    int i0 = blockIdx.x * blockDim.x + threadIdx.x;
    int stride = gridDim.x * blockDim.x;
    for (int t = i0; t < 768 * 256; t += stride) wqkv[t] = f2bf(qkv_w[t]);
    for (int t = i0; t < 256 * 256; t += stride) wproj[t] = f2bf(proj_w[t]);
    for (int t = i0; t < NH * 64 * 64; t += stride) {
        int h = t >> 12;
        int m = (t >> 6) & 63;   // query row
        int n = t & 63;          // key col
        float v;
        if (n >= NTOK)      v = -1e30f;
        else if (m >= NTOK) v = 0.0f;
        else                v = bias_table[rel_idx[m * NTOK + n] * NH + h];
        biasx[t] = v;
    }
}

// ---------------------------------------------------------------------------
// K1: fully fused per-window QKV + attention + proj. 256 thr = 4 waves.
// LDS 63488 B -> 2 blocks/CU.
//
// HW model from R0/R1/R2 counters (gfx950): effective regs/wave ~= 2x the
// reported VGPR_Count when MFMA is used (accum mirror in the unified file);
// waves/SIMD = floor(512 / (2*VGPR)). 512-thr blocks quantize badly (VGPR
// 65..128 -> 1 block/CU); 256-thr at VGPR<=128 gives the stable 2-block
// residency. __launch_bounds__ 2nd arg is CUDA-style min BLOCKS/CU on this
// toolchain (R1: (512,4) forced VGPR cap 64 + spills). (256,4) -> cap 128.
//
// Structure: 8 passes, ONE head per pass, double-buffered q/k/v staging
// (2 x 14848 B) so pass p's attention (buf p&1) overlaps pass p+1's QKV
// stage (buf (p+1)&1). ONE barrier per pass: 9 total (R0 had 13 + fence).
// P never touches LDS: in-register 16-lane-group shuffle transpose
// (verified in R2) feeds the PV B-fragment directly.
//
// Layout conventions (mfma_f32_16x16x32_bf16):
//   A-frag: a[m = lane&15][k = (lane>>4)*8 + j]
//   B-frag: b[n = lane&15][k = (lane>>4)*8 + j]
//   C/D   : col(n) = lane&15, row(m) = (lane>>4)*4 + reg
// ---------------------------------------------------------------------------
__global__ __launch_bounds__(256, 4) void fused_kernel(
    const float* __restrict__ x,
    const float* __restrict__ qkv_b,
    const unsigned short* __restrict__ wqkv,
    const float* __restrict__ biasx,
    const unsigned short* __restrict__ wproj,
    const float* __restrict__ proj_b,
    float* __restrict__ out)
{
    // ao [64][264] = 16896 shorts; then 2 staging buffers of 7424 shorts:
    //   qs[64][40] (2560) | ks[64][40] (2560) | vt[32][72] (2304)
    __shared__ unsigned short smem[31744];   // 63488 B total
    unsigned short* ao = smem;

    const int tid  = threadIdx.x;
    const int wv   = tid >> 6;           // 0..3
    const int lane = tid & 63;
    const int l16  = lane & 15;
    const int lq   = lane >> 4;
    const int w    = blockIdx.x;
    const float scale = 0.17677669529663687f;   // 32^-0.5

    const int wh = wv & 1;    // token half (QKV x-frags + proj store half)
    const int jt = wv >> 1;   // QKV job triple (0..1)
    const int qt = wv;        // attention: query 16-tile

    const float* xw = x + (size_t)w * (NTOK * 256);

    // ---- x B-fragments for this wave's token half (fp32 -> bf16), ONCE ----
    bf16x8 xfr[2][8];
#pragma unroll
    for (int nt = 0; nt < 2; ++nt) {
        int tok = wh * 32 + nt * 16 + l16;
#pragma unroll
        for (int c = 0; c < 8; ++c) {
            if (tok < NTOK) {
                const float* pp = xw + tok * 256 + c * 32 + lq * 8;
                float4 f0 = *(const float4*)pp;
                float4 f1 = *(const float4*)(pp + 4);
                xfr[nt][c] = pk8(f0, f1);
            } else {
                union { bf16x8 v; unsigned int u[4]; } z;
                z.u[0] = z.u[1] = z.u[2] = z.u[3] = 0;
                xfr[nt][c] = z.v;
            }
        }
    }

    // ---- QKV stage for head h into buffer b ----
    auto qkv_stage = [&](int h, int b) {
        unsigned short* qsb = smem + 16896 + b * 7424;
        unsigned short* ksb = qsb + 2560;
        unsigned short* vtb = qsb + 5120;
#pragma unroll
        for (int ti = 0; ti < 3; ++ti) {
            int tl   = jt * 3 + ti;            // 0..5: q,q,k,k,v,v
            int grp  = tl >> 1;                // 0=q 1=k 2=v
            int sub  = tl & 1;                 // which 16-ch tile of the head
            int tile = grp * 16 + 2 * h + sub; // of 48
            const unsigned short* bptr = wqkv + (size_t)(tile * 16 + l16) * 256 + lq * 8;
            bf16x8 bfr[8];
#pragma unroll
            for (int c = 0; c < 8; ++c) bfr[c] = ld8s(bptr + c * 32);

            f32x4 acc[2];
            { f32x4 z = {0.f,0.f,0.f,0.f}; acc[0] = z; acc[1] = z; }

            if (grp < 2) {
                // swapped: D[ch][tok] -> packed writes along d
#pragma unroll
                for (int c = 0; c < 8; ++c)
#pragma unroll
                    for (int nt = 0; nt < 2; ++nt)
                        acc[nt] = mfma16(bfr[c], xfr[nt][c], acc[nt]);
                int chb = tile * 16 + lq * 4;          // global channel base
                float4 bv = *(const float4*)(qkv_b + chb);
                int d0 = sub * 16 + lq * 4;            // channel within head
                unsigned short* dst = (grp == 0 ? qsb : ksb) + d0;
                float sc = (grp == 0) ? scale : 1.0f;
#pragma unroll
                for (int nt = 0; nt < 2; ++nt) {
                    int tok = wh * 32 + nt * 16 + l16;
                    st4bf(dst + tok * 40,
                          (acc[nt][0] + bv.x) * sc, (acc[nt][1] + bv.y) * sc,
                          (acc[nt][2] + bv.z) * sc, (acc[nt][3] + bv.w) * sc);
                }
            } else {
                // original: D[tok][ch] -> packed writes along tok into v^T
#pragma unroll
                for (int c = 0; c < 8; ++c)
#pragma unroll
                    for (int nt = 0; nt < 2; ++nt)
                        acc[nt] = mfma16(xfr[nt][c], bfr[c], acc[nt]);
                int ch = tile * 16 + l16;
                float bv = qkv_b[ch];
                int d = sub * 16 + l16;                // d within head
                unsigned short* dst = vtb + d * 72;
#pragma unroll
                for (int nt = 0; nt < 2; ++nt) {
                    int tok0 = wh * 32 + nt * 16 + lq * 4;
                    st4bf(dst + tok0, acc[nt][0] + bv, acc[nt][1] + bv,
                                      acc[nt][2] + bv, acc[nt][3] + bv);
                }
            }
        }
    };

    // prologue: stage head 0 into buffer 0
    qkv_stage(0, 0);
    __syncthreads();

#pragma unroll 1
    for (int p = 0; p < NH; ++p) {
        const int b = p & 1;
        unsigned short* qsb = smem + 16896 + b * 7424;
        unsigned short* ksb = qsb + 2560;
        unsigned short* vtb = qsb + 5120;

        // ================= attention head p: Sᵀ = K·Qᵀ =================
        bf16x8 kf[4];
#pragma unroll
        for (int mt = 0; mt < 4; ++mt)
            kf[mt] = ld8s(&ksb[(mt * 16 + l16) * 40 + lq * 8]);
        bf16x8 qf = ld8s(&qsb[(qt * 16 + l16) * 40 + lq * 8]);

        f32x4 se[4];
#pragma unroll
        for (int mt = 0; mt < 4; ++mt) { f32x4 z = {0.f,0.f,0.f,0.f}; se[mt] = z; }
#pragma unroll
        for (int mt = 0; mt < 4; ++mt)
            se[mt] = mfma16(kf[mt], qf, se[mt]);
        // lane holds: query = qt*16 + l16, key = mt*16 + lq*4 + r

        // bias + exp + in-lane sum (no max-subtract: |s| bounded ~15)
        const int q = qt * 16 + l16;
        const float* bh = biasx + (p << 12);
        float lsum = 0.0f;
#pragma unroll
        for (int mt = 0; mt < 4; ++mt) {
            float4 bb = *(const float4*)(bh + q * 64 + mt * 16 + lq * 4);
            float e0 = __expf(se[mt][0] + bb.x);
            float e1 = __expf(se[mt][1] + bb.y);
            float e2 = __expf(se[mt][2] + bb.z);
            float e3 = __expf(se[mt][3] + bb.w);
            se[mt][0] = e0; se[mt][1] = e1;
            se[mt][2] = e2; se[mt][3] = e3;
            lsum += (e0 + e1) + (e2 + e3);
        }
        lsum += __shfl_xor(lsum, 16);
        lsum += __shfl_xor(lsum, 32);
        float rv = 1.0f / lsum;

        // pack normalized P: P0[mt] = keys (lq*4+0,1), P1[mt] = keys (lq*4+2,3)
        unsigned int P0[4], P1[4];
#pragma unroll
        for (int mt = 0; mt < 4; ++mt) {
            P0[mt] = pk2bf(se[mt][0] * rv, se[mt][1] * rv);
            P1[mt] = pk2bf(se[mt][2] * rv, se[mt][3] * rv);
        }
        // redistribute to PV B-frag in-register (16-lane-group transpose):
        // pf[kc] dword dj holds keys kc*32 + lq*8 + 2*dj(+1); the owner of
        // key K is lane (l16, (K>>2)&3), regs P{0,1}[K>>4].
        int srcA = l16 + ((2 * lq) & 3) * 16;
        int srcB = srcA + 16;            // ((2*lq+1)&3)*16 == srcA+16 always
        int hi = lq >> 1;                // selects mt' = 2*kc + (lq>>1)
        bf16x8 pf[2];
#pragma unroll
        for (int kc = 0; kc < 2; ++kc) {
            unsigned int a0 = (unsigned int)__shfl((int)P0[2 * kc],     srcA);
            unsigned int a1 = (unsigned int)__shfl((int)P0[2 * kc + 1], srcA);
            unsigned int b0 = (unsigned int)__shfl((int)P1[2 * kc],     srcA);
            unsigned int b1 = (unsigned int)__shfl((int)P1[2 * kc + 1], srcA);
            unsigned int c0 = (unsigned int)__shfl((int)P0[2 * kc],     srcB);
            unsigned int c1 = (unsigned int)__shfl((int)P0[2 * kc + 1], srcB);
            unsigned int d0 = (unsigned int)__shfl((int)P1[2 * kc],     srcB);
            unsigned int d1 = (unsigned int)__shfl((int)P1[2 * kc + 1], srcB);
            union { bf16x8 v; unsigned int u[4]; } t;
            t.u[0] = hi ? a1 : a0;
            t.u[1] = hi ? b1 : b0;
            t.u[2] = hi ? c1 : c0;
            t.u[3] = hi ? d1 : d0;
            pf[kc] = t.v;
        }

        // ================= Oᵀ = Vᵀ·P =================
        bf16x8 vf[2][2];
#pragma unroll
        for (int kc = 0; kc < 2; ++kc)
#pragma unroll
            for (int mt = 0; mt < 2; ++mt)
                vf[mt][kc] = ld8s(&vtb[(mt * 16 + l16) * 72 + kc * 32 + lq * 8]);

        f32x4 ot[2];
        { f32x4 z = {0.f,0.f,0.f,0.f}; ot[0] = z; ot[1] = z; }
#pragma unroll
        for (int kc = 0; kc < 2; ++kc)
#pragma unroll
            for (int mt = 0; mt < 2; ++mt)
                ot[mt] = mfma16(vf[mt][kc], pf[kc], ot[mt]);
        // lane holds: d = mt*16 + lq*4 + r, query = qt*16 + l16

#pragma unroll
        for (int mt = 0; mt < 2; ++mt)
            st4bf(&ao[q * 264 + p * 32 + mt * 16 + lq * 4],
                  ot[mt][0], ot[mt][1], ot[mt][2], ot[mt][3]);

        // ====== overlap: stage next head into the other buffer ======
        if (p < NH - 1) qkv_stage(p + 1, b ^ 1);

        __syncthreads();   // staging visible; buf b reads done before reuse
    }

    // ================= projection from LDS attnout =================
    bf16x8 af2[4][8];
#pragma unroll
    for (int nt = 0; nt < 4; ++nt)
#pragma unroll
        for (int c = 0; c < 8; ++c)
            af2[nt][c] = ld8s(&ao[(nt * 16 + l16) * 264 + c * 32 + lq * 8]);

#pragma unroll
    for (int t4 = 0; t4 < 4; ++t4) {
        int tile = wv * 4 + t4;            // 16 channel-tiles
        const unsigned short* wp = wproj + (size_t)(tile * 16 + l16) * 256 + lq * 8;
        bf16x8 wfr[8];
#pragma unroll
        for (int c = 0; c < 8; ++c) wfr[c] = ld8s(wp + c * 32);

        f32x4 acc[4];
#pragma unroll
        for (int i = 0; i < 4; ++i) { f32x4 z = {0.f,0.f,0.f,0.f}; acc[i] = z; }
#pragma unroll
        for (int c = 0; c < 8; ++c)
#pragma unroll
            for (int nt = 0; nt < 4; ++nt)
                acc[nt] = mfma16(wfr[c], af2[nt][c], acc[nt]);

        int chb = tile * 16 + lq * 4;
        float4 pb = *(const float4*)(proj_b + chb);
#pragma unroll
        for (int nt = 0; nt < 4; ++nt) {
            int tok = nt * 16 + l16;
            if (tok < NTOK) {
                float4 o;
                o.x = acc[nt][0] + pb.x;
                o.y = acc[nt][1] + pb.y;
                o.z = acc[nt][2] + pb.z;
                o.w = acc[nt][3] + pb.w;
                *(float4*)(out + ((size_t)w * NTOK + tok) * 256 + chb) = o;
            }
        }
    }
}

// ---------------------------------------------------------------------------
extern "C" void kernel_launch(void* const* d_in, const int* in_sizes, int n_in,
                              void* d_out, int out_size, void* d_ws, size_t ws_size,
                              hipStream_t stream) {
    const float* x          = (const float*)d_in[0];
    const float* qkv_w      = (const float*)d_in[1];
    const float* qkv_b      = (const float*)d_in[2];
    const float* proj_w     = (const float*)d_in[3];
    const float* proj_b     = (const float*)d_in[4];
    const float* bias_table = (const float*)d_in[5];
    const int*   rel_idx    = (const int*)d_in[6];
    float* out = (float*)d_out;

    char* ws = (char*)d_ws;
    unsigned short* wqkv  = (unsigned short*)ws;                 // 393216 B
    unsigned short* wproj = (unsigned short*)(ws + 393216);      // 131072 B
    float*          biasx = (float*)(ws + 524288);               // 131072 B

    prep_kernel<<<256, 256, 0, stream>>>(qkv_w, proj_w, bias_table, rel_idx,
                                         wqkv, wproj, biasx);
    fused_kernel<<<NWIN, 256, 0, stream>>>(x, qkv_b, wqkv, biasx, wproj,
                                           proj_b, out);
}